// Round 1
// baseline (1493.109 us; speedup 1.0000x reference)
//
#include <hip/hip_runtime.h>

#define D 128
#define NCLS 10

static __device__ __forceinline__ float relu(float x){ return fmaxf(x, 0.0f); }

__global__ __launch_bounds__(256) void k_deg_init(float* __restrict__ deg, int n){
  int i = blockIdx.x*256 + threadIdx.x;
  if (i < n) deg[i] = 1.0f;
}

__global__ __launch_bounds__(256) void k_deg_count(const int* __restrict__ dst,
                                                   float* __restrict__ deg, int E){
  int i = blockIdx.x*256 + threadIdx.x;
  if (i < E) atomicAdd(deg + dst[i], 1.0f);
}

__global__ __launch_bounds__(256) void k_dinv(const float* __restrict__ deg,
                                              float* __restrict__ dinv, int n){
  int i = blockIdx.x*256 + threadIdx.x;
  if (i < n) dinv[i] = 1.0f / sqrtf(deg[i]);  // deg >= 1 (self-loop)
}

// C = maybe_relu(A) @ W ; A:[M,128], W:[128,128], C:[M,128], row-major f32.
// 32 rows/block; W staged in two 64-k phases (32KB LDS); 2x8 register tile.
__global__ __launch_bounds__(256) void k_gemm128(const float* __restrict__ A,
                                                 const float* __restrict__ W,
                                                 float* __restrict__ C,
                                                 int M, int doRelu){
  __shared__ float4 sW4[64*32];   // [k_local][c4]  32KB
  __shared__ float4 sA4[32*33];   // padded row stride 33 float4  16.9KB
  const int tid = threadIdx.x;
  const int row0 = blockIdx.x * 32;
  const float4* A4 = (const float4*)A + (size_t)row0 * 32;
  const int rowsHere = (M - row0 >= 32) ? 32 : (M - row0);
  const int nf4 = rowsHere * 32;
  for (int i = tid; i < 32*32; i += 256){
    float4 v = make_float4(0.f, 0.f, 0.f, 0.f);
    if (i < nf4) v = A4[i];
    if (doRelu){ v.x=relu(v.x); v.y=relu(v.y); v.z=relu(v.z); v.w=relu(v.w); }
    sA4[(i >> 5)*33 + (i & 31)] = v;
  }
  const int colg = tid & 15;   // 8 cols: [colg*4 .. +3] and [colg*4+64 .. +3]
  const int rowg = tid >> 4;   // 2 rows: 2*rowg, 2*rowg+1
  float4 acc00 = make_float4(0,0,0,0), acc01 = acc00, acc10 = acc00, acc11 = acc00;
  for (int ph = 0; ph < 2; ++ph){
    __syncthreads();                           // also protects sA on ph=0
    const float4* Wp = (const float4*)W + ph * (64*32);
    #pragma unroll
    for (int i = 0; i < 8; ++i) sW4[i*256 + tid] = Wp[i*256 + tid];
    __syncthreads();
    #pragma unroll 4
    for (int k4 = 0; k4 < 16; ++k4){
      float4 a0 = sA4[(2*rowg)*33   + ph*16 + k4];
      float4 a1 = sA4[(2*rowg+1)*33 + ph*16 + k4];
      #pragma unroll
      for (int kk = 0; kk < 4; ++kk){
        const int k = k4*4 + kk;               // local k in [0,64)
        float4 w0 = sW4[k*32 + colg];
        float4 w1 = sW4[k*32 + colg + 16];
        float av0 = ((const float*)&a0)[kk];
        float av1 = ((const float*)&a1)[kk];
        acc00.x += av0*w0.x; acc00.y += av0*w0.y; acc00.z += av0*w0.z; acc00.w += av0*w0.w;
        acc01.x += av0*w1.x; acc01.y += av0*w1.y; acc01.z += av0*w1.z; acc01.w += av0*w1.w;
        acc10.x += av1*w0.x; acc10.y += av1*w0.y; acc10.z += av1*w0.z; acc10.w += av1*w0.w;
        acc11.x += av1*w1.x; acc11.y += av1*w1.y; acc11.z += av1*w1.z; acc11.w += av1*w1.w;
      }
    }
  }
  float4* C4 = (float4*)C;
  const int r0 = row0 + 2*rowg;
  if (r0 < M){
    C4[(size_t)r0*32 + colg]      = acc00;
    C4[(size_t)r0*32 + colg + 16] = acc01;
  }
  if (r0 + 1 < M){
    C4[(size_t)(r0+1)*32 + colg]      = acc10;
    C4[(size_t)(r0+1)*32 + colg + 16] = acc11;
  }
}

// out[n][c] = h[n][c]*dinv[n]^2 + b[c]   (self-loop term + bias seeds accumulator)
__global__ __launch_bounds__(256) void k_seed(const float* __restrict__ h,
                                              const float* __restrict__ dinv,
                                              const float* __restrict__ b,
                                              float* __restrict__ out, int n){
  int i = blockIdx.x*256 + threadIdx.x;     // over n*32 float4
  if (i >= n*32) return;
  int node = i >> 5, q = i & 31;
  float di = dinv[node];
  float sl = di * di;
  float4 hv = ((const float4*)h)[i];
  float4 bv = ((const float4*)b)[q];
  float4 o;
  o.x = hv.x*sl + bv.x; o.y = hv.y*sl + bv.y;
  o.z = hv.z*sl + bv.z; o.w = hv.w*sl + bv.w;
  ((float4*)out)[i] = o;
}

// one wave per edge: out[dst] += h[src] * dinv[src]*dinv[dst]
__global__ __launch_bounds__(256) void k_aggregate(const float* __restrict__ h,
                                                   const int* __restrict__ src,
                                                   const int* __restrict__ dst,
                                                   const float* __restrict__ dinv,
                                                   float* __restrict__ out, int E){
  int gid = blockIdx.x*256 + threadIdx.x;
  int e = gid >> 6;
  int lane = gid & 63;
  if (e >= E) return;
  int s = src[e], d = dst[e];
  float norm = dinv[s] * dinv[d];
  const float2* hr = (const float2*)(h + (size_t)s * D);
  float2 v = hr[lane];
  float* orow = out + (size_t)d * D;
  atomicAdd(orow + 2*lane,     v.x * norm);
  atomicAdd(orow + 2*lane + 1, v.y * norm);
}

// one wave per row: logits = relu(h) @ Wl + bl; write log_softmax
__global__ __launch_bounds__(256) void k_head(const float* __restrict__ h,
                                              const float* __restrict__ Wl,
                                              const float* __restrict__ bl,
                                              float* __restrict__ out, int n){
  int gid = blockIdx.x*256 + threadIdx.x;
  int row = gid >> 6;
  int lane = gid & 63;
  if (row >= n) return;
  float hl = relu(h[(size_t)row*D + lane]);
  float hh = relu(h[(size_t)row*D + 64 + lane]);
  float acc[NCLS];
  #pragma unroll
  for (int c = 0; c < NCLS; ++c)
    acc[c] = hl * Wl[lane*NCLS + c] + hh * Wl[(64 + lane)*NCLS + c];
  #pragma unroll
  for (int c = 0; c < NCLS; ++c){
    #pragma unroll
    for (int off = 32; off >= 1; off >>= 1)
      acc[c] += __shfl_xor(acc[c], off, 64);
    acc[c] += bl[c];
  }
  float m = acc[0];
  #pragma unroll
  for (int c = 1; c < NCLS; ++c) m = fmaxf(m, acc[c]);
  float se = 0.f;
  #pragma unroll
  for (int c = 0; c < NCLS; ++c) se += expf(acc[c] - m);
  float lse = m + logf(se);
  if (lane < NCLS){
    float v = acc[0];
    #pragma unroll
    for (int c = 1; c < NCLS; ++c) if (lane == c) v = acc[c];
    out[(size_t)row*NCLS + lane] = v - lse;
  }
}

extern "C" void kernel_launch(void* const* d_in, const int* in_sizes, int n_in,
                              void* d_out, int out_size, void* d_ws, size_t ws_size,
                              hipStream_t stream){
  const float* x  = (const float*)d_in[0];
  const int*   ei = (const int*)d_in[1];
  const float* W1 = (const float*)d_in[2];
  const float* b1 = (const float*)d_in[3];
  const float* W2 = (const float*)d_in[4];
  const float* b2 = (const float*)d_in[5];
  const float* Wl = (const float*)d_in[6];
  const float* bl = (const float*)d_in[7];
  float* out = (float*)d_out;

  const int N = in_sizes[0] / D;     // 50000
  const int E = in_sizes[1] / 2;     // 800000
  const int* src = ei;
  const int* dst = ei + E;

  char* ws = (char*)d_ws;
  float* bufA = (float*)ws;                                    // N*D f32
  float* bufB = (float*)(ws + (size_t)N*D*4);                  // N*D f32
  float* deg  = (float*)(ws + (size_t)2*N*D*4);                // N f32
  float* dinv = (float*)(ws + (size_t)2*N*D*4 + (size_t)N*4);  // N f32

  const int nbN    = (N + 255)/256;
  const int nbE    = (E + 255)/256;
  const int gemmB  = (N + 31)/32;
  const int seedB  = (N*32 + 255)/256;
  const int aggB   = (E + 3)/4;      // 1 wave per edge, 4 waves/block
  const int headB  = (N + 3)/4;      // 1 wave per row

  k_deg_init<<<nbN, 256, 0, stream>>>(deg, N);
  k_deg_count<<<nbE, 256, 0, stream>>>(dst, deg, E);
  k_dinv<<<nbN, 256, 0, stream>>>(deg, dinv, N);

  // layer 1
  k_gemm128<<<gemmB, 256, 0, stream>>>(x, W1, bufA, N, 0);
  k_seed<<<seedB, 256, 0, stream>>>(bufA, dinv, b1, bufB, N);
  k_aggregate<<<aggB, 256, 0, stream>>>(bufA, src, dst, dinv, bufB, E);

  // layer 2 (relu of layer-1 output fused into GEMM A-load)
  k_gemm128<<<gemmB, 256, 0, stream>>>(bufB, W2, bufA, N, 1);
  k_seed<<<seedB, 256, 0, stream>>>(bufA, dinv, b2, bufB, N);
  k_aggregate<<<aggB, 256, 0, stream>>>(bufA, src, dst, dinv, bufB, E);

  // head: relu + @Wl + bl + log_softmax
  k_head<<<headB, 256, 0, stream>>>(bufB, Wl, bl, out, N);
}

// Round 2
// 407.274 us; speedup vs baseline: 3.6661x; 3.6661x over previous
//
#include <hip/hip_runtime.h>

#define D 128
#define NCLS 10

static __device__ __forceinline__ float relu(float x){ return fmaxf(x, 0.0f); }

__global__ __launch_bounds__(256) void k_zero_i32(int* __restrict__ p, int n){
  int i = blockIdx.x*256 + threadIdx.x;
  if (i < n) p[i] = 0;
}

__global__ __launch_bounds__(256) void k_hist(const int* __restrict__ dst,
                                              int* __restrict__ counts, int E){
  int i = blockIdx.x*256 + threadIdx.x;
  if (i < E) atomicAdd(counts + dst[i], 1);
}

// exclusive scan of counts[0..n) -> rowPtr[0..n], single block of 1024
__global__ __launch_bounds__(1024) void k_scan(const int* __restrict__ counts,
                                               int* __restrict__ rowPtr, int n){
  __shared__ int part[1024];
  const int t = threadIdx.x;
  const int chunk = (n + 1023) / 1024;
  const int lo = t * chunk;
  const int hi = (lo + chunk < n) ? lo + chunk : n;
  int s = 0;
  for (int i = lo; i < hi; ++i) s += counts[i];
  part[t] = s;
  __syncthreads();
  for (int off = 1; off < 1024; off <<= 1){
    int u = (t >= off) ? part[t - off] : 0;
    __syncthreads();
    part[t] += u;
    __syncthreads();
  }
  int excl = part[t] - s;               // exclusive prefix for this chunk
  for (int i = lo; i < hi; ++i){ rowPtr[i] = excl; excl += counts[i]; }
  if (t == 1023) rowPtr[n] = part[1023];
}

__global__ __launch_bounds__(256) void k_dinv(const int* __restrict__ counts,
                                              float* __restrict__ dinv, int n){
  int i = blockIdx.x*256 + threadIdx.x;
  if (i < n) dinv[i] = rsqrtf((float)(counts[i] + 1));  // +1 self-loop
}

__global__ __launch_bounds__(256) void k_scatter(const int* __restrict__ src,
                                                 const int* __restrict__ dst,
                                                 const int* __restrict__ rowPtr,
                                                 int* __restrict__ cursor,
                                                 int* __restrict__ srcs, int E){
  int i = blockIdx.x*256 + threadIdx.x;
  if (i >= E) return;
  int d = dst[i];
  int pos = rowPtr[d] + atomicAdd(cursor + d, 1);
  srcs[pos] = src[i];
}

// C = maybe_relu(A) @ W ; A:[M,128], W:[128,128], C:[M,128], row-major f32.
__global__ __launch_bounds__(256) void k_gemm128(const float* __restrict__ A,
                                                 const float* __restrict__ W,
                                                 float* __restrict__ C,
                                                 int M, int doRelu){
  __shared__ float4 sW4[64*32];   // [k_local][c4]  32KB
  __shared__ float4 sA4[32*33];   // padded row stride 33 float4
  const int tid = threadIdx.x;
  const int row0 = blockIdx.x * 32;
  const float4* A4 = (const float4*)A + (size_t)row0 * 32;
  const int rowsHere = (M - row0 >= 32) ? 32 : (M - row0);
  const int nf4 = rowsHere * 32;
  for (int i = tid; i < 32*32; i += 256){
    float4 v = make_float4(0.f, 0.f, 0.f, 0.f);
    if (i < nf4) v = A4[i];
    if (doRelu){ v.x=relu(v.x); v.y=relu(v.y); v.z=relu(v.z); v.w=relu(v.w); }
    sA4[(i >> 5)*33 + (i & 31)] = v;
  }
  const int colg = tid & 15;
  const int rowg = tid >> 4;
  float4 acc00 = make_float4(0,0,0,0), acc01 = acc00, acc10 = acc00, acc11 = acc00;
  for (int ph = 0; ph < 2; ++ph){
    __syncthreads();
    const float4* Wp = (const float4*)W + ph * (64*32);
    #pragma unroll
    for (int i = 0; i < 8; ++i) sW4[i*256 + tid] = Wp[i*256 + tid];
    __syncthreads();
    #pragma unroll 4
    for (int k4 = 0; k4 < 16; ++k4){
      float4 a0 = sA4[(2*rowg)*33   + ph*16 + k4];
      float4 a1 = sA4[(2*rowg+1)*33 + ph*16 + k4];
      #pragma unroll
      for (int kk = 0; kk < 4; ++kk){
        const int k = k4*4 + kk;
        float4 w0 = sW4[k*32 + colg];
        float4 w1 = sW4[k*32 + colg + 16];
        float av0 = ((const float*)&a0)[kk];
        float av1 = ((const float*)&a1)[kk];
        acc00.x += av0*w0.x; acc00.y += av0*w0.y; acc00.z += av0*w0.z; acc00.w += av0*w0.w;
        acc01.x += av0*w1.x; acc01.y += av0*w1.y; acc01.z += av0*w1.z; acc01.w += av0*w1.w;
        acc10.x += av1*w0.x; acc10.y += av1*w0.y; acc10.z += av1*w0.z; acc10.w += av1*w0.w;
        acc11.x += av1*w1.x; acc11.y += av1*w1.y; acc11.z += av1*w1.z; acc11.w += av1*w1.w;
      }
    }
  }
  float4* C4 = (float4*)C;
  const int r0 = row0 + 2*rowg;
  if (r0 < M){
    C4[(size_t)r0*32 + colg]      = acc00;
    C4[(size_t)r0*32 + colg + 16] = acc01;
  }
  if (r0 + 1 < M){
    C4[(size_t)(r0+1)*32 + colg]      = acc10;
    C4[(size_t)(r0+1)*32 + colg + 16] = acc11;
  }
}

// one wave per node: out[n] = h[n]*dinv[n]^2 + b + sum_{j in CSR[n]} h[srcs[j]]*dinv[srcs[j]]*dinv[n]
__global__ __launch_bounds__(256) void k_agg_csr(const float* __restrict__ h,
                                                 const int* __restrict__ rowPtr,
                                                 const int* __restrict__ srcs,
                                                 const float* __restrict__ dinv,
                                                 const float* __restrict__ b,
                                                 float* __restrict__ out, int n){
  int gid = blockIdx.x*256 + threadIdx.x;
  int node = gid >> 6;
  int lane = gid & 63;
  if (node >= n) return;
  float dn = dinv[node];
  float sl = dn * dn;
  float2 hv = ((const float2*)(h + (size_t)node*D))[lane];
  float2 bv = ((const float2*)b)[lane];
  float ax = hv.x*sl + bv.x;
  float ay = hv.y*sl + bv.y;
  int beg = rowPtr[node], end = rowPtr[node+1];
  for (int j = beg; j < end; j += 64){
    int rem = end - j;
    int cnt = (rem < 64) ? rem : 64;
    int s = 0; float ds = 0.f;
    if (lane < cnt){ s = srcs[j + lane]; ds = dinv[s]; }
    for (int kk = 0; kk < cnt; ++kk){
      int   sb = __shfl(s,  kk);
      float nb = __shfl(ds, kk) * dn;
      float2 hs = ((const float2*)(h + (size_t)sb*D))[lane];
      ax += hs.x * nb;
      ay += hs.y * nb;
    }
  }
  ((float2*)(out + (size_t)node*D))[lane] = make_float2(ax, ay);
}

// one wave per row: logits = relu(h) @ Wl + bl; write log_softmax
__global__ __launch_bounds__(256) void k_head(const float* __restrict__ h,
                                              const float* __restrict__ Wl,
                                              const float* __restrict__ bl,
                                              float* __restrict__ out, int n){
  int gid = blockIdx.x*256 + threadIdx.x;
  int row = gid >> 6;
  int lane = gid & 63;
  if (row >= n) return;
  float hl = relu(h[(size_t)row*D + lane]);
  float hh = relu(h[(size_t)row*D + 64 + lane]);
  float acc[NCLS];
  #pragma unroll
  for (int c = 0; c < NCLS; ++c)
    acc[c] = hl * Wl[lane*NCLS + c] + hh * Wl[(64 + lane)*NCLS + c];
  #pragma unroll
  for (int c = 0; c < NCLS; ++c){
    #pragma unroll
    for (int off = 32; off >= 1; off >>= 1)
      acc[c] += __shfl_xor(acc[c], off, 64);
    acc[c] += bl[c];
  }
  float m = acc[0];
  #pragma unroll
  for (int c = 1; c < NCLS; ++c) m = fmaxf(m, acc[c]);
  float se = 0.f;
  #pragma unroll
  for (int c = 0; c < NCLS; ++c) se += expf(acc[c] - m);
  float lse = m + logf(se);
  if (lane < NCLS){
    float v = acc[0];
    #pragma unroll
    for (int c = 1; c < NCLS; ++c) if (lane == c) v = acc[c];
    out[(size_t)row*NCLS + lane] = v - lse;
  }
}

extern "C" void kernel_launch(void* const* d_in, const int* in_sizes, int n_in,
                              void* d_out, int out_size, void* d_ws, size_t ws_size,
                              hipStream_t stream){
  const float* x  = (const float*)d_in[0];
  const int*   ei = (const int*)d_in[1];
  const float* W1 = (const float*)d_in[2];
  const float* b1 = (const float*)d_in[3];
  const float* W2 = (const float*)d_in[4];
  const float* b2 = (const float*)d_in[5];
  const float* Wl = (const float*)d_in[6];
  const float* bl = (const float*)d_in[7];
  float* out = (float*)d_out;

  const int N = in_sizes[0] / D;     // 50000
  const int E = in_sizes[1] / 2;     // 800000
  const int* src = ei;
  const int* dst = ei + E;

  char* ws = (char*)d_ws;
  size_t off = 0;
  float* bufA   = (float*)(ws + off); off += (size_t)N*D*4;
  float* bufB   = (float*)(ws + off); off += (size_t)N*D*4;
  int*   counts = (int*)(ws + off);   off += (size_t)N*4;
  int*   cursor = (int*)(ws + off);   off += (size_t)N*4;   // adjacent to counts
  int*   rowPtr = (int*)(ws + off);   off += (size_t)(N+1)*4;
  float* dinv   = (float*)(ws + off); off += (size_t)N*4;
  int*   srcs   = (int*)(ws + off);   off += (size_t)E*4;

  const int nbN   = (N + 255)/256;
  const int nb2N  = (2*N + 255)/256;
  const int nbE   = (E + 255)/256;
  const int gemmB = (N + 31)/32;
  const int aggB  = (N + 3)/4;       // 1 wave per node
  const int headB = (N + 3)/4;

  // CSR build (counts and cursor are adjacent -> one zero pass)
  k_zero_i32<<<nb2N, 256, 0, stream>>>(counts, 2*N);
  k_hist<<<nbE, 256, 0, stream>>>(dst, counts, E);
  k_scan<<<1, 1024, 0, stream>>>(counts, rowPtr, N);
  k_dinv<<<nbN, 256, 0, stream>>>(counts, dinv, N);
  k_scatter<<<nbE, 256, 0, stream>>>(src, dst, rowPtr, cursor, srcs, E);

  // layer 1
  k_gemm128<<<gemmB, 256, 0, stream>>>(x, W1, bufA, N, 0);
  k_agg_csr<<<aggB, 256, 0, stream>>>(bufA, rowPtr, srcs, dinv, b1, bufB, N);

  // layer 2 (relu fused into GEMM A-load)
  k_gemm128<<<gemmB, 256, 0, stream>>>(bufB, W2, bufA, N, 1);
  k_agg_csr<<<aggB, 256, 0, stream>>>(bufA, rowPtr, srcs, dinv, b2, bufB, N);

  // head
  k_head<<<headB, 256, 0, stream>>>(bufB, Wl, bl, out, N);
}

// Round 3
// 335.831 us; speedup vs baseline: 4.4460x; 1.2127x over previous
//
#include <hip/hip_runtime.h>

#define D 128
#define NCLS 10

static __device__ __forceinline__ float relu(float x){ return fmaxf(x, 0.0f); }

__global__ __launch_bounds__(256) void k_zero_i32(int* __restrict__ p, int n){
  int i = blockIdx.x*256 + threadIdx.x;
  if (i < n) p[i] = 0;
}

__global__ __launch_bounds__(256) void k_hist(const int* __restrict__ dst,
                                              int* __restrict__ counts, int E){
  int i = blockIdx.x*256 + threadIdx.x;
  if (i < E) atomicAdd(counts + dst[i], 1);
}

// scan phase 1: per-block exclusive scan of counts into rowPtr; block sums out
__global__ __launch_bounds__(256) void k_scan1(const int* __restrict__ counts,
                                               int* __restrict__ rowPtr,
                                               int* __restrict__ bsum, int n){
  const int i = blockIdx.x*256 + threadIdx.x;
  const int lane = threadIdx.x & 63;
  const int wid  = threadIdx.x >> 6;
  int v = (i < n) ? counts[i] : 0;
  int s = v;
  #pragma unroll
  for (int off = 1; off < 64; off <<= 1){
    int u = __shfl_up(s, off, 64);
    if (lane >= off) s += u;
  }
  __shared__ int ws[4];
  if (lane == 63) ws[wid] = s;
  __syncthreads();
  int add = 0;
  if (wid >= 1) add += ws[0];
  if (wid >= 2) add += ws[1];
  if (wid >= 3) add += ws[2];
  int incl = s + add;
  if (i < n) rowPtr[i] = incl - v;            // block-local exclusive
  if (threadIdx.x == 255) bsum[blockIdx.x] = incl;  // block total
}

// scan phase 2: single block scans block sums (nb <= 256) exclusively in place
__global__ __launch_bounds__(256) void k_scan2(int* __restrict__ bsum,
                                               int* __restrict__ rowPtr,
                                               int nb, int n){
  const int t = threadIdx.x;
  const int lane = t & 63;
  const int wid  = t >> 6;
  int v = (t < nb) ? bsum[t] : 0;
  int s = v;
  #pragma unroll
  for (int off = 1; off < 64; off <<= 1){
    int u = __shfl_up(s, off, 64);
    if (lane >= off) s += u;
  }
  __shared__ int ws[4];
  if (lane == 63) ws[wid] = s;
  __syncthreads();
  int add = 0;
  if (wid >= 1) add += ws[0];
  if (wid >= 2) add += ws[1];
  if (wid >= 3) add += ws[2];
  int incl = s + add;
  if (t < nb) bsum[t] = incl - v;             // exclusive block offset
  if (t == 255) rowPtr[n] = incl;             // grand total (padding = 0)
}

// scan phase 3: add block offsets; fuse dinv = rsqrt(count+1)
__global__ __launch_bounds__(256) void k_scan3(const int* __restrict__ counts,
                                               const int* __restrict__ bsum,
                                               int* __restrict__ rowPtr,
                                               float* __restrict__ dinv, int n){
  int i = blockIdx.x*256 + threadIdx.x;
  if (i >= n) return;
  rowPtr[i] += bsum[blockIdx.x];
  dinv[i] = rsqrtf((float)(counts[i] + 1));
}

__global__ __launch_bounds__(256) void k_scatter(const int* __restrict__ src,
                                                 const int* __restrict__ dst,
                                                 const int* __restrict__ rowPtr,
                                                 int* __restrict__ cursor,
                                                 int* __restrict__ srcs, int E){
  int i = blockIdx.x*256 + threadIdx.x;
  if (i >= E) return;
  int d = dst[i];
  int pos = rowPtr[d] + atomicAdd(cursor + d, 1);
  srcs[pos] = src[i];
}

// C = maybe_relu(A) @ W ; A:[M,128], W:[128,128], C:[M,128], row-major f32.
__global__ __launch_bounds__(256) void k_gemm128(const float* __restrict__ A,
                                                 const float* __restrict__ W,
                                                 float* __restrict__ C,
                                                 int M, int doRelu){
  __shared__ float4 sW4[64*32];   // [k_local][c4]  32KB
  __shared__ float4 sA4[32*33];   // padded row stride 33 float4
  const int tid = threadIdx.x;
  const int row0 = blockIdx.x * 32;
  const float4* A4 = (const float4*)A + (size_t)row0 * 32;
  const int rowsHere = (M - row0 >= 32) ? 32 : (M - row0);
  const int nf4 = rowsHere * 32;
  for (int i = tid; i < 32*32; i += 256){
    float4 v = make_float4(0.f, 0.f, 0.f, 0.f);
    if (i < nf4) v = A4[i];
    if (doRelu){ v.x=relu(v.x); v.y=relu(v.y); v.z=relu(v.z); v.w=relu(v.w); }
    sA4[(i >> 5)*33 + (i & 31)] = v;
  }
  const int colg = tid & 15;
  const int rowg = tid >> 4;
  float4 acc00 = make_float4(0,0,0,0), acc01 = acc00, acc10 = acc00, acc11 = acc00;
  for (int ph = 0; ph < 2; ++ph){
    __syncthreads();
    const float4* Wp = (const float4*)W + ph * (64*32);
    #pragma unroll
    for (int i = 0; i < 8; ++i) sW4[i*256 + tid] = Wp[i*256 + tid];
    __syncthreads();
    #pragma unroll 4
    for (int k4 = 0; k4 < 16; ++k4){
      float4 a0 = sA4[(2*rowg)*33   + ph*16 + k4];
      float4 a1 = sA4[(2*rowg+1)*33 + ph*16 + k4];
      #pragma unroll
      for (int kk = 0; kk < 4; ++kk){
        const int k = k4*4 + kk;
        float4 w0 = sW4[k*32 + colg];
        float4 w1 = sW4[k*32 + colg + 16];
        float av0 = ((const float*)&a0)[kk];
        float av1 = ((const float*)&a1)[kk];
        acc00.x += av0*w0.x; acc00.y += av0*w0.y; acc00.z += av0*w0.z; acc00.w += av0*w0.w;
        acc01.x += av0*w1.x; acc01.y += av0*w1.y; acc01.z += av0*w1.z; acc01.w += av0*w1.w;
        acc10.x += av1*w0.x; acc10.y += av1*w0.y; acc10.z += av1*w0.z; acc10.w += av1*w0.w;
        acc11.x += av1*w1.x; acc11.y += av1*w1.y; acc11.z += av1*w1.z; acc11.w += av1*w1.w;
      }
    }
  }
  float4* C4 = (float4*)C;
  const int r0 = row0 + 2*rowg;
  if (r0 < M){
    C4[(size_t)r0*32 + colg]      = acc00;
    C4[(size_t)r0*32 + colg + 16] = acc01;
  }
  if (r0 + 1 < M){
    C4[(size_t)(r0+1)*32 + colg]      = acc10;
    C4[(size_t)(r0+1)*32 + colg + 16] = acc11;
  }
}

// one wave per node: out[n] = h[n]*dinv[n]^2 + b + sum_{j in CSR[n]} h[srcs[j]]*dinv[srcs[j]]*dinv[n]
__global__ __launch_bounds__(256) void k_agg_csr(const float* __restrict__ h,
                                                 const int* __restrict__ rowPtr,
                                                 const int* __restrict__ srcs,
                                                 const float* __restrict__ dinv,
                                                 const float* __restrict__ b,
                                                 float* __restrict__ out, int n){
  int gid = blockIdx.x*256 + threadIdx.x;
  int node = gid >> 6;
  int lane = gid & 63;
  if (node >= n) return;
  float dn = dinv[node];
  float sl = dn * dn;
  float2 hv = ((const float2*)(h + (size_t)node*D))[lane];
  float2 bv = ((const float2*)b)[lane];
  float ax = hv.x*sl + bv.x;
  float ay = hv.y*sl + bv.y;
  int beg = rowPtr[node], end = rowPtr[node+1];
  for (int j = beg; j < end; j += 64){
    int rem = end - j;
    int cnt = (rem < 64) ? rem : 64;
    int s = 0; float ds = 0.f;
    if (lane < cnt){ s = srcs[j + lane]; ds = dinv[s]; }
    for (int kk = 0; kk < cnt; ++kk){
      int   sb = __shfl(s,  kk);
      float nb = __shfl(ds, kk) * dn;
      float2 hs = ((const float2*)(h + (size_t)sb*D))[lane];
      ax += hs.x * nb;
      ay += hs.y * nb;
    }
  }
  ((float2*)(out + (size_t)node*D))[lane] = make_float2(ax, ay);
}

// one wave per row: logits = relu(h) @ Wl + bl; write log_softmax
__global__ __launch_bounds__(256) void k_head(const float* __restrict__ h,
                                              const float* __restrict__ Wl,
                                              const float* __restrict__ bl,
                                              float* __restrict__ out, int n){
  int gid = blockIdx.x*256 + threadIdx.x;
  int row = gid >> 6;
  int lane = gid & 63;
  if (row >= n) return;
  float hl = relu(h[(size_t)row*D + lane]);
  float hh = relu(h[(size_t)row*D + 64 + lane]);
  float acc[NCLS];
  #pragma unroll
  for (int c = 0; c < NCLS; ++c)
    acc[c] = hl * Wl[lane*NCLS + c] + hh * Wl[(64 + lane)*NCLS + c];
  #pragma unroll
  for (int c = 0; c < NCLS; ++c){
    #pragma unroll
    for (int off = 32; off >= 1; off >>= 1)
      acc[c] += __shfl_xor(acc[c], off, 64);
    acc[c] += bl[c];
  }
  float m = acc[0];
  #pragma unroll
  for (int c = 1; c < NCLS; ++c) m = fmaxf(m, acc[c]);
  float se = 0.f;
  #pragma unroll
  for (int c = 0; c < NCLS; ++c) se += expf(acc[c] - m);
  float lse = m + logf(se);
  if (lane < NCLS){
    float v = acc[0];
    #pragma unroll
    for (int c = 1; c < NCLS; ++c) if (lane == c) v = acc[c];
    out[(size_t)row*NCLS + lane] = v - lse;
  }
}

extern "C" void kernel_launch(void* const* d_in, const int* in_sizes, int n_in,
                              void* d_out, int out_size, void* d_ws, size_t ws_size,
                              hipStream_t stream){
  const float* x  = (const float*)d_in[0];
  const int*   ei = (const int*)d_in[1];
  const float* W1 = (const float*)d_in[2];
  const float* b1 = (const float*)d_in[3];
  const float* W2 = (const float*)d_in[4];
  const float* b2 = (const float*)d_in[5];
  const float* Wl = (const float*)d_in[6];
  const float* bl = (const float*)d_in[7];
  float* out = (float*)d_out;

  const int N = in_sizes[0] / D;     // 50000
  const int E = in_sizes[1] / 2;     // 800000
  const int* src = ei;
  const int* dst = ei + E;

  char* ws = (char*)d_ws;
  size_t off = 0;
  float* bufA   = (float*)(ws + off); off += (size_t)N*D*4;
  float* bufB   = (float*)(ws + off); off += (size_t)N*D*4;
  int*   counts = (int*)(ws + off);   off += (size_t)N*4;
  int*   cursor = (int*)(ws + off);   off += (size_t)N*4;   // adjacent to counts
  int*   rowPtr = (int*)(ws + off);   off += (size_t)(N+1)*4;
  float* dinv   = (float*)(ws + off); off += (size_t)N*4;
  int*   bsum   = (int*)(ws + off);   off += (size_t)256*4;
  int*   srcs   = (int*)(ws + off);   off += (size_t)E*4;

  const int nbN   = (N + 255)/256;   // 196 (<=256, fits k_scan2's single block)
  const int nb2N  = (2*N + 255)/256;
  const int nbE   = (E + 255)/256;
  const int gemmB = (N + 31)/32;
  const int aggB  = (N + 3)/4;       // 1 wave per node
  const int headB = (N + 3)/4;

  // CSR build
  k_zero_i32<<<nb2N, 256, 0, stream>>>(counts, 2*N);   // counts + cursor
  k_hist<<<nbE, 256, 0, stream>>>(dst, counts, E);
  k_scan1<<<nbN, 256, 0, stream>>>(counts, rowPtr, bsum, N);
  k_scan2<<<1, 256, 0, stream>>>(bsum, rowPtr, nbN, N);
  k_scan3<<<nbN, 256, 0, stream>>>(counts, bsum, rowPtr, dinv, N);
  k_scatter<<<nbE, 256, 0, stream>>>(src, dst, rowPtr, cursor, srcs, E);

  // layer 1
  k_gemm128<<<gemmB, 256, 0, stream>>>(x, W1, bufA, N, 0);
  k_agg_csr<<<aggB, 256, 0, stream>>>(bufA, rowPtr, srcs, dinv, b1, bufB, N);

  // layer 2 (relu fused into GEMM A-load)
  k_gemm128<<<gemmB, 256, 0, stream>>>(bufB, W2, bufA, N, 1);
  k_agg_csr<<<aggB, 256, 0, stream>>>(bufA, rowPtr, srcs, dinv, b2, bufB, N);

  // head
  k_head<<<headB, 256, 0, stream>>>(bufB, Wl, bl, out, N);
}

// Round 4
// 287.724 us; speedup vs baseline: 5.1894x; 1.1672x over previous
//
#include <hip/hip_runtime.h>

#define D 128
#define NCLS 10

static __device__ __forceinline__ float relu(float x){ return fmaxf(x, 0.0f); }

__global__ __launch_bounds__(256) void k_zero_i32(int* __restrict__ p, int n){
  int i = blockIdx.x*256 + threadIdx.x;
  if (i < n) p[i] = 0;
}

__global__ __launch_bounds__(256) void k_hist(const int* __restrict__ dst,
                                              int* __restrict__ counts, int E){
  int i = blockIdx.x*256 + threadIdx.x;
  if (i < E) atomicAdd(counts + dst[i], 1);
}

// scan phase 1: per-block exclusive scan of counts into rowPtr; block sums out
__global__ __launch_bounds__(256) void k_scan1(const int* __restrict__ counts,
                                               int* __restrict__ rowPtr,
                                               int* __restrict__ bsum, int n){
  const int i = blockIdx.x*256 + threadIdx.x;
  const int lane = threadIdx.x & 63;
  const int wid  = threadIdx.x >> 6;
  int v = (i < n) ? counts[i] : 0;
  int s = v;
  #pragma unroll
  for (int off = 1; off < 64; off <<= 1){
    int u = __shfl_up(s, off, 64);
    if (lane >= off) s += u;
  }
  __shared__ int ws[4];
  if (lane == 63) ws[wid] = s;
  __syncthreads();
  int add = 0;
  if (wid >= 1) add += ws[0];
  if (wid >= 2) add += ws[1];
  if (wid >= 3) add += ws[2];
  int incl = s + add;
  if (i < n) rowPtr[i] = incl - v;            // block-local exclusive
  if (threadIdx.x == 255) bsum[blockIdx.x] = incl;  // block total
}

// scan phase 2: single block scans block sums (nb <= 256) exclusively in place
__global__ __launch_bounds__(256) void k_scan2(int* __restrict__ bsum,
                                               int* __restrict__ rowPtr,
                                               int nb, int n){
  const int t = threadIdx.x;
  const int lane = t & 63;
  const int wid  = t >> 6;
  int v = (t < nb) ? bsum[t] : 0;
  int s = v;
  #pragma unroll
  for (int off = 1; off < 64; off <<= 1){
    int u = __shfl_up(s, off, 64);
    if (lane >= off) s += u;
  }
  __shared__ int ws[4];
  if (lane == 63) ws[wid] = s;
  __syncthreads();
  int add = 0;
  if (wid >= 1) add += ws[0];
  if (wid >= 2) add += ws[1];
  if (wid >= 3) add += ws[2];
  int incl = s + add;
  if (t < nb) bsum[t] = incl - v;             // exclusive block offset
  if (t == 255) rowPtr[n] = incl;             // grand total (padding = 0)
}

// scan phase 3: add block offsets; fuse dinv = rsqrt(count+1)
__global__ __launch_bounds__(256) void k_scan3(const int* __restrict__ counts,
                                               const int* __restrict__ bsum,
                                               int* __restrict__ rowPtr,
                                               float* __restrict__ dinv, int n){
  int i = blockIdx.x*256 + threadIdx.x;
  if (i >= n) return;
  rowPtr[i] += bsum[blockIdx.x];
  dinv[i] = rsqrtf((float)(counts[i] + 1));
}

__global__ __launch_bounds__(256) void k_scatter(const int* __restrict__ src,
                                                 const int* __restrict__ dst,
                                                 const int* __restrict__ rowPtr,
                                                 int* __restrict__ cursor,
                                                 int* __restrict__ srcs, int E){
  int i = blockIdx.x*256 + threadIdx.x;
  if (i >= E) return;
  int d = dst[i];
  int pos = rowPtr[d] + atomicAdd(cursor + d, 1);
  srcs[pos] = src[i];
}

// C = maybe_relu(A) @ W ; A:[M,128], W:[128,128], C:[M,128], row-major f32.
__global__ __launch_bounds__(256) void k_gemm128(const float* __restrict__ A,
                                                 const float* __restrict__ W,
                                                 float* __restrict__ C,
                                                 int M, int doRelu){
  __shared__ float4 sW4[64*32];   // [k_local][c4]  32KB
  __shared__ float4 sA4[32*33];   // padded row stride 33 float4
  const int tid = threadIdx.x;
  const int row0 = blockIdx.x * 32;
  const float4* A4 = (const float4*)A + (size_t)row0 * 32;
  const int rowsHere = (M - row0 >= 32) ? 32 : (M - row0);
  const int nf4 = rowsHere * 32;
  for (int i = tid; i < 32*32; i += 256){
    float4 v = make_float4(0.f, 0.f, 0.f, 0.f);
    if (i < nf4) v = A4[i];
    if (doRelu){ v.x=relu(v.x); v.y=relu(v.y); v.z=relu(v.z); v.w=relu(v.w); }
    sA4[(i >> 5)*33 + (i & 31)] = v;
  }
  const int colg = tid & 15;
  const int rowg = tid >> 4;
  float4 acc00 = make_float4(0,0,0,0), acc01 = acc00, acc10 = acc00, acc11 = acc00;
  for (int ph = 0; ph < 2; ++ph){
    __syncthreads();
    const float4* Wp = (const float4*)W + ph * (64*32);
    #pragma unroll
    for (int i = 0; i < 8; ++i) sW4[i*256 + tid] = Wp[i*256 + tid];
    __syncthreads();
    #pragma unroll 4
    for (int k4 = 0; k4 < 16; ++k4){
      float4 a0 = sA4[(2*rowg)*33   + ph*16 + k4];
      float4 a1 = sA4[(2*rowg+1)*33 + ph*16 + k4];
      #pragma unroll
      for (int kk = 0; kk < 4; ++kk){
        const int k = k4*4 + kk;
        float4 w0 = sW4[k*32 + colg];
        float4 w1 = sW4[k*32 + colg + 16];
        float av0 = ((const float*)&a0)[kk];
        float av1 = ((const float*)&a1)[kk];
        acc00.x += av0*w0.x; acc00.y += av0*w0.y; acc00.z += av0*w0.z; acc00.w += av0*w0.w;
        acc01.x += av0*w1.x; acc01.y += av0*w1.y; acc01.z += av0*w1.z; acc01.w += av0*w1.w;
        acc10.x += av1*w0.x; acc10.y += av1*w0.y; acc10.z += av1*w0.z; acc10.w += av1*w0.w;
        acc11.x += av1*w1.x; acc11.y += av1*w1.y; acc11.z += av1*w1.z; acc11.w += av1*w1.w;
      }
    }
  }
  float4* C4 = (float4*)C;
  const int r0 = row0 + 2*rowg;
  if (r0 < M){
    C4[(size_t)r0*32 + colg]      = acc00;
    C4[(size_t)r0*32 + colg + 16] = acc01;
  }
  if (r0 + 1 < M){
    C4[(size_t)(r0+1)*32 + colg]      = acc10;
    C4[(size_t)(r0+1)*32 + colg + 16] = acc11;
  }
}

// Wide-gather aggregation core: 2 edges per step (32 lanes x float4 each),
// unrolled x4, padding steps neutralized by ds=0. Returns combined row in
// lanes 0..31 (float4 at quad q), including self-loop + bias.
#define AGG_CORE(ACCOUT)                                                      \
  const int half = lane >> 5;                                                 \
  const int q    = lane & 31;                                                 \
  float dn = dinv[node];                                                      \
  float4 a0 = make_float4(0,0,0,0), a1 = a0;                                  \
  int beg = rowPtr[node], end = rowPtr[node+1];                               \
  for (int j = beg; j < end; j += 64){                                        \
    int rem = end - j;                                                        \
    int cnt = (rem < 64) ? rem : 64;                                          \
    int s = 0; float ds = 0.f;                                                \
    if (lane < cnt){ s = srcs[j + lane]; ds = dinv[s]; }                      \
    int tcnt4 = (((cnt + 1) >> 1) + 3) & ~3;                                  \
    for (int t = 0; t < tcnt4; t += 4){                                       \
      _Pragma("unroll")                                                       \
      for (int u = 0; u < 4; ++u){                                            \
        int e = 2*(t+u) + half;                                               \
        int sb = __shfl(s, e);                                                \
        float nb = __shfl(ds, e) * dn;                                        \
        float4 hv = ((const float4*)(h + (size_t)sb*D))[q];                   \
        float4& ac = (u & 1) ? a1 : a0;                                       \
        ac.x += hv.x*nb; ac.y += hv.y*nb; ac.z += hv.z*nb; ac.w += hv.w*nb;   \
      }                                                                       \
    }                                                                         \
  }                                                                           \
  float4 ACCOUT;                                                              \
  ACCOUT.x = a0.x + a1.x; ACCOUT.y = a0.y + a1.y;                             \
  ACCOUT.z = a0.z + a1.z; ACCOUT.w = a0.w + a1.w;                             \
  ACCOUT.x += __shfl_xor(ACCOUT.x, 32, 64);                                   \
  ACCOUT.y += __shfl_xor(ACCOUT.y, 32, 64);                                   \
  ACCOUT.z += __shfl_xor(ACCOUT.z, 32, 64);                                   \
  ACCOUT.w += __shfl_xor(ACCOUT.w, 32, 64);

// layer-1 agg: out[node] = h*dinv^2 + b + gathered; f32 row store
__global__ __launch_bounds__(256) void k_agg_csr(const float* __restrict__ h,
                                                 const int* __restrict__ rowPtr,
                                                 const int* __restrict__ srcs,
                                                 const float* __restrict__ dinv,
                                                 const float* __restrict__ b,
                                                 float* __restrict__ out, int n){
  int gid = blockIdx.x*256 + threadIdx.x;
  int node = gid >> 6;
  int lane = gid & 63;
  if (node >= n) return;
  AGG_CORE(acc)
  if (half == 0){
    float4 hs = ((const float4*)(h + (size_t)node*D))[q];
    float4 bv = ((const float4*)b)[q];
    float sl = dn * dn;
    acc.x += hs.x*sl + bv.x; acc.y += hs.y*sl + bv.y;
    acc.z += hs.z*sl + bv.z; acc.w += hs.w*sl + bv.w;
    ((float4*)(out + (size_t)node*D))[q] = acc;
  }
}

// layer-2 agg fused with head: relu(agg) @ Wl + bl -> log_softmax -> out[node][10]
__global__ __launch_bounds__(256) void k_agg_head(const float* __restrict__ h,
                                                  const int* __restrict__ rowPtr,
                                                  const int* __restrict__ srcs,
                                                  const float* __restrict__ dinv,
                                                  const float* __restrict__ b,
                                                  const float* __restrict__ Wl,
                                                  const float* __restrict__ bl,
                                                  float* __restrict__ out, int n){
  int gid = blockIdx.x*256 + threadIdx.x;
  int node = gid >> 6;
  int lane = gid & 63;
  if (node >= n) return;
  AGG_CORE(acc)
  if (half) return;                 // upper half done (combine already used it)
  float4 hs = ((const float4*)(h + (size_t)node*D))[q];
  float4 bv = ((const float4*)b)[q];
  float sl = dn * dn;
  float4 r;
  r.x = relu(acc.x + hs.x*sl + bv.x);
  r.y = relu(acc.y + hs.y*sl + bv.y);
  r.z = relu(acc.z + hs.z*sl + bv.z);
  r.w = relu(acc.w + hs.w*sl + bv.w);
  float lacc[NCLS];
  #pragma unroll
  for (int c = 0; c < NCLS; ++c){
    lacc[c] = r.x * Wl[(4*q+0)*NCLS + c] + r.y * Wl[(4*q+1)*NCLS + c]
            + r.z * Wl[(4*q+2)*NCLS + c] + r.w * Wl[(4*q+3)*NCLS + c];
  }
  #pragma unroll
  for (int c = 0; c < NCLS; ++c){
    #pragma unroll
    for (int off = 16; off >= 1; off >>= 1)
      lacc[c] += __shfl_xor(lacc[c], off, 32);
    lacc[c] += bl[c];
  }
  float m = lacc[0];
  #pragma unroll
  for (int c = 1; c < NCLS; ++c) m = fmaxf(m, lacc[c]);
  float se = 0.f;
  #pragma unroll
  for (int c = 0; c < NCLS; ++c) se += expf(lacc[c] - m);
  float lse = m + logf(se);
  if (q < NCLS){
    float v = lacc[0];
    #pragma unroll
    for (int c = 1; c < NCLS; ++c) if (q == c) v = lacc[c];
    out[(size_t)node*NCLS + q] = v - lse;
  }
}

extern "C" void kernel_launch(void* const* d_in, const int* in_sizes, int n_in,
                              void* d_out, int out_size, void* d_ws, size_t ws_size,
                              hipStream_t stream){
  const float* x  = (const float*)d_in[0];
  const int*   ei = (const int*)d_in[1];
  const float* W1 = (const float*)d_in[2];
  const float* b1 = (const float*)d_in[3];
  const float* W2 = (const float*)d_in[4];
  const float* b2 = (const float*)d_in[5];
  const float* Wl = (const float*)d_in[6];
  const float* bl = (const float*)d_in[7];
  float* out = (float*)d_out;

  const int N = in_sizes[0] / D;     // 50000
  const int E = in_sizes[1] / 2;     // 800000
  const int* src = ei;
  const int* dst = ei + E;

  char* ws = (char*)d_ws;
  size_t off = 0;
  float* bufA   = (float*)(ws + off); off += (size_t)N*D*4;
  float* bufB   = (float*)(ws + off); off += (size_t)N*D*4;
  int*   counts = (int*)(ws + off);   off += (size_t)N*4;
  int*   cursor = (int*)(ws + off);   off += (size_t)N*4;   // adjacent to counts
  int*   rowPtr = (int*)(ws + off);   off += (size_t)(N+1)*4;
  float* dinv   = (float*)(ws + off); off += (size_t)N*4;
  int*   bsum   = (int*)(ws + off);   off += (size_t)256*4;
  int*   srcs   = (int*)(ws + off);   off += (size_t)E*4;

  const int nbN   = (N + 255)/256;   // 196 (<=256, fits k_scan2's single block)
  const int nb2N  = (2*N + 255)/256;
  const int nbE   = (E + 255)/256;
  const int gemmB = (N + 31)/32;
  const int aggB  = (N + 3)/4;       // 1 wave per node

  // CSR build
  k_zero_i32<<<nb2N, 256, 0, stream>>>(counts, 2*N);   // counts + cursor
  k_hist<<<nbE, 256, 0, stream>>>(dst, counts, E);
  k_scan1<<<nbN, 256, 0, stream>>>(counts, rowPtr, bsum, N);
  k_scan2<<<1, 256, 0, stream>>>(bsum, rowPtr, nbN, N);
  k_scan3<<<nbN, 256, 0, stream>>>(counts, bsum, rowPtr, dinv, N);
  k_scatter<<<nbE, 256, 0, stream>>>(src, dst, rowPtr, cursor, srcs, E);

  // layer 1
  k_gemm128<<<gemmB, 256, 0, stream>>>(x, W1, bufA, N, 0);
  k_agg_csr<<<aggB, 256, 0, stream>>>(bufA, rowPtr, srcs, dinv, b1, bufB, N);

  // layer 2 (relu fused into GEMM A-load; head fused into aggregation)
  k_gemm128<<<gemmB, 256, 0, stream>>>(bufB, W2, bufA, N, 1);
  k_agg_head<<<aggB, 256, 0, stream>>>(bufA, rowPtr, srcs, dinv, b2, Wl, bl, out, N);
}

// Round 5
// 255.104 us; speedup vs baseline: 5.8529x; 1.1279x over previous
//
#include <hip/hip_runtime.h>
#include <hip/hip_bf16.h>

#define D 128
#define NCLS 10

static __device__ __forceinline__ float relu(float x){ return fmaxf(x, 0.0f); }
static __device__ __forceinline__ float bf_lo(unsigned v){ return __uint_as_float(v << 16); }
static __device__ __forceinline__ float bf_hi(unsigned v){ return __uint_as_float(v & 0xffff0000u); }

__global__ __launch_bounds__(256) void k_zero_i32(int* __restrict__ p, int n){
  int i = blockIdx.x*256 + threadIdx.x;
  if (i < n) p[i] = 0;
}

__global__ __launch_bounds__(256) void k_hist(const int* __restrict__ dst,
                                              int* __restrict__ counts, int E){
  int i = blockIdx.x*256 + threadIdx.x;
  if (i < E) atomicAdd(counts + dst[i], 1);
}

__global__ __launch_bounds__(256) void k_scan1(const int* __restrict__ counts,
                                               int* __restrict__ rowPtr,
                                               int* __restrict__ bsum, int n){
  const int i = blockIdx.x*256 + threadIdx.x;
  const int lane = threadIdx.x & 63;
  const int wid  = threadIdx.x >> 6;
  int v = (i < n) ? counts[i] : 0;
  int s = v;
  #pragma unroll
  for (int off = 1; off < 64; off <<= 1){
    int u = __shfl_up(s, off, 64);
    if (lane >= off) s += u;
  }
  __shared__ int ws[4];
  if (lane == 63) ws[wid] = s;
  __syncthreads();
  int add = 0;
  if (wid >= 1) add += ws[0];
  if (wid >= 2) add += ws[1];
  if (wid >= 3) add += ws[2];
  int incl = s + add;
  if (i < n) rowPtr[i] = incl - v;
  if (threadIdx.x == 255) bsum[blockIdx.x] = incl;
}

__global__ __launch_bounds__(256) void k_scan2(int* __restrict__ bsum,
                                               int* __restrict__ rowPtr,
                                               int nb, int n){
  const int t = threadIdx.x;
  const int lane = t & 63;
  const int wid  = t >> 6;
  int v = (t < nb) ? bsum[t] : 0;
  int s = v;
  #pragma unroll
  for (int off = 1; off < 64; off <<= 1){
    int u = __shfl_up(s, off, 64);
    if (lane >= off) s += u;
  }
  __shared__ int ws[4];
  if (lane == 63) ws[wid] = s;
  __syncthreads();
  int add = 0;
  if (wid >= 1) add += ws[0];
  if (wid >= 2) add += ws[1];
  if (wid >= 3) add += ws[2];
  int incl = s + add;
  if (t < nb) bsum[t] = incl - v;
  if (t == 255) rowPtr[n] = incl;
}

__global__ __launch_bounds__(256) void k_scan3(const int* __restrict__ counts,
                                               const int* __restrict__ bsum,
                                               int* __restrict__ rowPtr,
                                               float* __restrict__ dinv, int n){
  int i = blockIdx.x*256 + threadIdx.x;
  if (i >= n) return;
  rowPtr[i] += bsum[blockIdx.x];
  dinv[i] = rsqrtf((float)(counts[i] + 1));
}

__global__ __launch_bounds__(256) void k_scatter(const int* __restrict__ src,
                                                 const int* __restrict__ dst,
                                                 const int* __restrict__ rowPtr,
                                                 int* __restrict__ cursor,
                                                 int* __restrict__ srcs, int E){
  int i = blockIdx.x*256 + threadIdx.x;
  if (i >= E) return;
  int d = dst[i];
  int pos = rowPtr[d] + atomicAdd(cursor + d, 1);
  srcs[pos] = src[i];
}

// C(bf16) = maybe_relu(A(f32)) @ W(f32); A:[M,128], W:[128,128], C:[M,128]
__global__ __launch_bounds__(256) void k_gemm128(const float* __restrict__ A,
                                                 const float* __restrict__ W,
                                                 __hip_bfloat16* __restrict__ C,
                                                 int M, int doRelu){
  __shared__ float4 sW4[64*32];   // [k_local][c4]  32KB
  __shared__ float4 sA4[32*33];   // padded row stride 33 float4
  const int tid = threadIdx.x;
  const int row0 = blockIdx.x * 32;
  const float4* A4 = (const float4*)A + (size_t)row0 * 32;
  const int rowsHere = (M - row0 >= 32) ? 32 : (M - row0);
  const int nf4 = rowsHere * 32;
  for (int i = tid; i < 32*32; i += 256){
    float4 v = make_float4(0.f, 0.f, 0.f, 0.f);
    if (i < nf4) v = A4[i];
    if (doRelu){ v.x=relu(v.x); v.y=relu(v.y); v.z=relu(v.z); v.w=relu(v.w); }
    sA4[(i >> 5)*33 + (i & 31)] = v;
  }
  const int colg = tid & 15;
  const int rowg = tid >> 4;
  float4 acc00 = make_float4(0,0,0,0), acc01 = acc00, acc10 = acc00, acc11 = acc00;
  for (int ph = 0; ph < 2; ++ph){
    __syncthreads();
    const float4* Wp = (const float4*)W + ph * (64*32);
    #pragma unroll
    for (int i = 0; i < 8; ++i) sW4[i*256 + tid] = Wp[i*256 + tid];
    __syncthreads();
    #pragma unroll 4
    for (int k4 = 0; k4 < 16; ++k4){
      float4 a0 = sA4[(2*rowg)*33   + ph*16 + k4];
      float4 a1 = sA4[(2*rowg+1)*33 + ph*16 + k4];
      #pragma unroll
      for (int kk = 0; kk < 4; ++kk){
        const int k = k4*4 + kk;
        float4 w0 = sW4[k*32 + colg];
        float4 w1 = sW4[k*32 + colg + 16];
        float av0 = ((const float*)&a0)[kk];
        float av1 = ((const float*)&a1)[kk];
        acc00.x += av0*w0.x; acc00.y += av0*w0.y; acc00.z += av0*w0.z; acc00.w += av0*w0.w;
        acc01.x += av0*w1.x; acc01.y += av0*w1.y; acc01.z += av0*w1.z; acc01.w += av0*w1.w;
        acc10.x += av1*w0.x; acc10.y += av1*w0.y; acc10.z += av1*w0.z; acc10.w += av1*w0.w;
        acc11.x += av1*w1.x; acc11.y += av1*w1.y; acc11.z += av1*w1.z; acc11.w += av1*w1.w;
      }
    }
  }
  union Pack { ushort4 u; __hip_bfloat16 b[4]; };
  ushort4* C4 = (ushort4*)C;
  const int r0 = row0 + 2*rowg;
  if (r0 < M){
    Pack p0, p1;
    p0.b[0]=__float2bfloat16(acc00.x); p0.b[1]=__float2bfloat16(acc00.y);
    p0.b[2]=__float2bfloat16(acc00.z); p0.b[3]=__float2bfloat16(acc00.w);
    p1.b[0]=__float2bfloat16(acc01.x); p1.b[1]=__float2bfloat16(acc01.y);
    p1.b[2]=__float2bfloat16(acc01.z); p1.b[3]=__float2bfloat16(acc01.w);
    C4[(size_t)r0*32 + colg]      = p0.u;
    C4[(size_t)r0*32 + colg + 16] = p1.u;
  }
  if (r0 + 1 < M){
    Pack p0, p1;
    p0.b[0]=__float2bfloat16(acc10.x); p0.b[1]=__float2bfloat16(acc10.y);
    p0.b[2]=__float2bfloat16(acc10.z); p0.b[3]=__float2bfloat16(acc10.w);
    p1.b[0]=__float2bfloat16(acc11.x); p1.b[1]=__float2bfloat16(acc11.y);
    p1.b[2]=__float2bfloat16(acc11.z); p1.b[3]=__float2bfloat16(acc11.w);
    C4[(size_t)(r0+1)*32 + colg]      = p0.u;
    C4[(size_t)(r0+1)*32 + colg + 16] = p1.u;
  }
}

// bf16 gather core: 4 edges/step (16 lanes x uint4 = 256B row each), unroll 2.
// After the macro: lanes hold combined f32 acc for elems [q*8 .. q*8+7] in
// rA (elems 0-3 of the eighth... rA=elems q*8..+3, rB=q*8+4..+7), all lanes.
#define AGG_CORE_BF16                                                          \
  const int grp = lane >> 4;                                                   \
  const int q   = lane & 15;                                                   \
  float dn = dinv[node];                                                       \
  float4 aA0 = make_float4(0,0,0,0), aB0 = aA0, aA1 = aA0, aB1 = aA0;          \
  int beg = rowPtr[node], end = rowPtr[node+1];                                \
  for (int j = beg; j < end; j += 64){                                         \
    int rem = end - j;                                                         \
    int cnt = (rem < 64) ? rem : 64;                                           \
    int s = 0; float ds = 0.f;                                                 \
    if (lane < cnt){ s = srcs[j + lane]; ds = dinv[s]; }                       \
    int T = (((cnt + 3) >> 2) + 1) & ~1;                                       \
    for (int t = 0; t < T; t += 2){                                            \
      _Pragma("unroll")                                                        \
      for (int u = 0; u < 2; ++u){                                             \
        int e = 4*(t+u) + grp;                                                 \
        int sb = __shfl(s, e);                                                 \
        float nb = __shfl(ds, e) * dn;                                         \
        uint4 hv = ((const uint4*)(h + (size_t)sb*D))[q];                      \
        float4& cA = u ? aA1 : aA0;                                            \
        float4& cB = u ? aB1 : aB0;                                            \
        cA.x += bf_lo(hv.x)*nb; cA.y += bf_hi(hv.x)*nb;                        \
        cA.z += bf_lo(hv.y)*nb; cA.w += bf_hi(hv.y)*nb;                        \
        cB.x += bf_lo(hv.z)*nb; cB.y += bf_hi(hv.z)*nb;                        \
        cB.z += bf_lo(hv.w)*nb; cB.w += bf_hi(hv.w)*nb;                        \
      }                                                                        \
    }                                                                          \
  }                                                                            \
  float4 rA, rB;                                                               \
  rA.x=aA0.x+aA1.x; rA.y=aA0.y+aA1.y; rA.z=aA0.z+aA1.z; rA.w=aA0.w+aA1.w;      \
  rB.x=aB0.x+aB1.x; rB.y=aB0.y+aB1.y; rB.z=aB0.z+aB1.z; rB.w=aB0.w+aB1.w;      \
  rA.x += __shfl_xor(rA.x,16,64); rA.y += __shfl_xor(rA.y,16,64);              \
  rA.z += __shfl_xor(rA.z,16,64); rA.w += __shfl_xor(rA.w,16,64);              \
  rB.x += __shfl_xor(rB.x,16,64); rB.y += __shfl_xor(rB.y,16,64);              \
  rB.z += __shfl_xor(rB.z,16,64); rB.w += __shfl_xor(rB.w,16,64);              \
  rA.x += __shfl_xor(rA.x,32,64); rA.y += __shfl_xor(rA.y,32,64);              \
  rA.z += __shfl_xor(rA.z,32,64); rA.w += __shfl_xor(rA.w,32,64);              \
  rB.x += __shfl_xor(rB.x,32,64); rB.y += __shfl_xor(rB.y,32,64);              \
  rB.z += __shfl_xor(rB.z,32,64); rB.w += __shfl_xor(rB.w,32,64);

// layer-1 agg: out(f32)[node] = h*dinv^2 + b + gathered
__global__ __launch_bounds__(256) void k_agg_csr(const ushort* __restrict__ h,
                                                 const int* __restrict__ rowPtr,
                                                 const int* __restrict__ srcs,
                                                 const float* __restrict__ dinv,
                                                 const float* __restrict__ b,
                                                 float* __restrict__ out, int n){
  int gid = blockIdx.x*256 + threadIdx.x;
  int node = gid >> 6;
  int lane = gid & 63;
  if (node >= n) return;
  AGG_CORE_BF16
  if (grp != 0) return;
  uint4 hs = ((const uint4*)(h + (size_t)node*D))[q];
  float sl = dn * dn;
  float4 bA = ((const float4*)b)[2*q];
  float4 bB = ((const float4*)b)[2*q + 1];
  rA.x += bf_lo(hs.x)*sl + bA.x; rA.y += bf_hi(hs.x)*sl + bA.y;
  rA.z += bf_lo(hs.y)*sl + bA.z; rA.w += bf_hi(hs.y)*sl + bA.w;
  rB.x += bf_lo(hs.z)*sl + bB.x; rB.y += bf_hi(hs.z)*sl + bB.y;
  rB.z += bf_lo(hs.w)*sl + bB.w - bB.w + bB.z; rB.w += bf_hi(hs.w)*sl + bB.w;
  float4* o4 = (float4*)(out + (size_t)node*D);
  o4[2*q]     = rA;
  o4[2*q + 1] = rB;
}

// layer-2 agg fused with head: relu(agg) @ Wl + bl -> log_softmax
__global__ __launch_bounds__(256) void k_agg_head(const ushort* __restrict__ h,
                                                  const int* __restrict__ rowPtr,
                                                  const int* __restrict__ srcs,
                                                  const float* __restrict__ dinv,
                                                  const float* __restrict__ b,
                                                  const float* __restrict__ Wl,
                                                  const float* __restrict__ bl,
                                                  float* __restrict__ out, int n){
  int gid = blockIdx.x*256 + threadIdx.x;
  int node = gid >> 6;
  int lane = gid & 63;
  if (node >= n) return;
  AGG_CORE_BF16
  if (grp != 0) return;
  uint4 hs = ((const uint4*)(h + (size_t)node*D))[q];
  float sl = dn * dn;
  float4 bA = ((const float4*)b)[2*q];
  float4 bB = ((const float4*)b)[2*q + 1];
  float r[8];
  r[0] = relu(rA.x + bf_lo(hs.x)*sl + bA.x);
  r[1] = relu(rA.y + bf_hi(hs.x)*sl + bA.y);
  r[2] = relu(rA.z + bf_lo(hs.y)*sl + bA.z);
  r[3] = relu(rA.w + bf_hi(hs.y)*sl + bA.w);
  r[4] = relu(rB.x + bf_lo(hs.z)*sl + bB.x);
  r[5] = relu(rB.y + bf_hi(hs.z)*sl + bB.y);
  r[6] = relu(rB.z + bf_lo(hs.w)*sl + bB.z);
  r[7] = relu(rB.w + bf_hi(hs.w)*sl + bB.w);
  float lacc[NCLS];
  #pragma unroll
  for (int c = 0; c < NCLS; ++c){
    float a = 0.f;
    #pragma unroll
    for (int i = 0; i < 8; ++i) a += r[i] * Wl[(8*q + i)*NCLS + c];
    lacc[c] = a;
  }
  #pragma unroll
  for (int c = 0; c < NCLS; ++c){
    #pragma unroll
    for (int off = 8; off >= 1; off >>= 1)
      lacc[c] += __shfl_xor(lacc[c], off, 16);
    lacc[c] += bl[c];
  }
  float m = lacc[0];
  #pragma unroll
  for (int c = 1; c < NCLS; ++c) m = fmaxf(m, lacc[c]);
  float se = 0.f;
  #pragma unroll
  for (int c = 0; c < NCLS; ++c) se += expf(lacc[c] - m);
  float lse = m + logf(se);
  if (q < NCLS){
    float v = lacc[0];
    #pragma unroll
    for (int c = 1; c < NCLS; ++c) if (q == c) v = lacc[c];
    out[(size_t)node*NCLS + q] = v - lse;
  }
}

extern "C" void kernel_launch(void* const* d_in, const int* in_sizes, int n_in,
                              void* d_out, int out_size, void* d_ws, size_t ws_size,
                              hipStream_t stream){
  const float* x  = (const float*)d_in[0];
  const int*   ei = (const int*)d_in[1];
  const float* W1 = (const float*)d_in[2];
  const float* b1 = (const float*)d_in[3];
  const float* W2 = (const float*)d_in[4];
  const float* b2 = (const float*)d_in[5];
  const float* Wl = (const float*)d_in[6];
  const float* bl = (const float*)d_in[7];
  float* out = (float*)d_out;

  const int N = in_sizes[0] / D;     // 50000
  const int E = in_sizes[1] / 2;     // 800000
  const int* src = ei;
  const int* dst = ei + E;

  char* ws = (char*)d_ws;
  size_t off = 0;
  ushort* hbuf  = (ushort*)(ws + off); off += (size_t)N*D*2;   // bf16 GEMM out
  float* bufB   = (float*)(ws + off);  off += (size_t)N*D*4;   // f32 layer-1 out
  int*   counts = (int*)(ws + off);    off += (size_t)N*4;
  int*   cursor = (int*)(ws + off);    off += (size_t)N*4;
  int*   rowPtr = (int*)(ws + off);    off += (size_t)(N+1)*4;
  float* dinv   = (float*)(ws + off);  off += (size_t)N*4;
  int*   bsum   = (int*)(ws + off);    off += (size_t)256*4;
  int*   srcs   = (int*)(ws + off);    off += (size_t)E*4;

  const int nbN   = (N + 255)/256;
  const int nb2N  = (2*N + 255)/256;
  const int nbE   = (E + 255)/256;
  const int gemmB = (N + 31)/32;
  const int aggB  = (N + 3)/4;

  // CSR build
  k_zero_i32<<<nb2N, 256, 0, stream>>>(counts, 2*N);
  k_hist<<<nbE, 256, 0, stream>>>(dst, counts, E);
  k_scan1<<<nbN, 256, 0, stream>>>(counts, rowPtr, bsum, N);
  k_scan2<<<1, 256, 0, stream>>>(bsum, rowPtr, nbN, N);
  k_scan3<<<nbN, 256, 0, stream>>>(counts, bsum, rowPtr, dinv, N);
  k_scatter<<<nbE, 256, 0, stream>>>(src, dst, rowPtr, cursor, srcs, E);

  // layer 1
  k_gemm128<<<gemmB, 256, 0, stream>>>(x, W1, (__hip_bfloat16*)hbuf, N, 0);
  k_agg_csr<<<aggB, 256, 0, stream>>>(hbuf, rowPtr, srcs, dinv, b1, bufB, N);

  // layer 2
  k_gemm128<<<gemmB, 256, 0, stream>>>(bufB, W2, (__hip_bfloat16*)hbuf, N, 1);
  k_agg_head<<<aggB, 256, 0, stream>>>(hbuf, rowPtr, srcs, dinv, b2, Wl, bl, out, N);
}